// Round 14
// baseline (269.563 us; speedup 1.0000x reference)
//
#include <hip/hip_runtime.h>
#include <math.h>

// GCN 2-layer + FC + global_add_pool + log_softmax.
// Round 14 = R12 (R13's gather+FC fusion REVERTED: VGPR 56 -> 28% occupancy
// killed the gather, 74us vs 38us split) + dispatch-count harvest:
//  - bscan_k dropped: place_k recomputes the 391-bucket scan in LDS (reuses
//    lcur post-placement); node_k block-reduces gbcnt[0..bk) for its [s,e).
//    Cross-kernel coherence makes gbcnt visible; no intra-kernel sync.
//  - logsm_k dropped: final_k's last block (threadfence + device counter +
//    agent-scope atomic loads of pooled) computes log_softmax inline.
// 10 -> 8 dispatches; R11->R12 measured ~7us per dispatch eliminated.

#define NF_IN 128
#define HID1 16
#define BSH 8                 // 256 nodes per coarse bucket
#define BPB 256
#define EPB 8192              // edges per partition block
#define MAXNB 1024
#define XSP 132               // padded LDS stride for xw1

// ---- pass A: LDS hist -> cntmat row; zero pooled + done ----
__global__ __launch_bounds__(1024) void cnt1_k(const int* __restrict__ col,
                                               int* __restrict__ cntmat,
                                               float* __restrict__ pooled,
                                               int* __restrict__ done,
                                               int E, int N, int nb) {
    __shared__ int lh[MAXNB];
    int t = threadIdx.x;
    if (blockIdx.x == 0) {
        if (t < 2) pooled[t] = 0.0f;
        if (t == 2) *done = 0;
    }
    for (int i = t; i < nb; i += 1024) lh[i] = 0;
    __syncthreads();
    int base = blockIdx.x * EPB;
    #pragma unroll
    for (int k = 0; k < EPB / 1024; ++k) {
        int e = base + k * 1024 + t;
        if (e < E) {
            int c = col[e];
            if ((unsigned)c < (unsigned)N) atomicAdd(&lh[c >> BSH], 1);
        }
    }
    __syncthreads();
    int* rowp = cntmat + (size_t)blockIdx.x * nb;
    for (int i = t; i < nb; i += 1024) rowp[i] = lh[i];
}

// ---- pass B: wave-per-bucket column scan of cntmat (in place) ->
//      per-block exclusive offsets; bucket totals -> gbcnt ----
__global__ __launch_bounds__(256) void pscan2_k(int* __restrict__ cntmat,
                                                int* __restrict__ gbcnt,
                                                int nblk, int nb) {
    int wave = (blockIdx.x * blockDim.x + threadIdx.x) >> 6;
    int lane = threadIdx.x & 63;
    if (wave >= nb) return;
    int run = 0;
    for (int k0 = 0; k0 < nblk; k0 += 64) {
        int k = k0 + lane;
        int v = (k < nblk) ? cntmat[(size_t)k * nb + wave] : 0;
        int incl = v;
        #pragma unroll
        for (int off = 1; off < 64; off <<= 1) {
            int u = __shfl_up(incl, off, 64);
            if (lane >= off) incl += u;
        }
        int excl = incl - v + run;
        if (k < nblk) cntmat[(size_t)k * nb + wave] = excl;
        run += __shfl(incl, 63, 64);
    }
    if (lane == 0) gbcnt[wave] = run;
}

// ---- pass C: block-local LDS counting sort; bucket-scan computed in-block;
//      line-dense copy-out ----
__global__ __launch_bounds__(1024) void place_k(const int* __restrict__ row,
                                                const int* __restrict__ col,
                                                const int* __restrict__ gbcnt,
                                                const int* __restrict__ cntmat,
                                                int* __restrict__ staging,
                                                int E, int N, int nb) {
    __shared__ int lh[MAXNB];            // counts -> later global dest base
    __shared__ int lstart[MAXNB];        // local exclusive offsets
    __shared__ int lcur[MAXNB];          // local cursors -> later bstarts scan
    __shared__ int lstage[EPB];          // 32 KB: locally sorted packed edges
    __shared__ unsigned short lbuck[EPB];// 16 KB: bucket of each local slot
    __shared__ int stot;
    int t = threadIdx.x;
    for (int i = t; i < nb; i += 1024) lh[i] = 0;
    __syncthreads();
    int base = blockIdx.x * EPB;
    int r[8], c[8];
    #pragma unroll
    for (int k = 0; k < 8; ++k) {
        int e = base + k * 1024 + t;
        if (e < E) {
            r[k] = row[e];
            c[k] = col[e];
            if ((unsigned)r[k] < (unsigned)N && (unsigned)c[k] < (unsigned)N)
                atomicAdd(&lh[c[k] >> BSH], 1);
            else r[k] = -1;
        } else r[k] = -1;
    }
    __syncthreads();
    // exclusive scan of lh over nb (nb <= 1024)
    int v = (t < nb) ? lh[t] : 0;
    lstart[t] = v;
    __syncthreads();
    for (int off = 1; off < 1024; off <<= 1) {
        int u = (t >= off) ? lstart[t - off] : 0;
        __syncthreads();
        lstart[t] += u;
        __syncthreads();
    }
    int excl = lstart[t] - v;   // own slot only
    __syncthreads();
    lstart[t] = excl;
    lcur[t] = excl;
    if (t == nb - 1) stot = excl + v;
    __syncthreads();
    // local placement grouped by bucket
    #pragma unroll
    for (int k = 0; k < 8; ++k) {
        if (r[k] >= 0) {
            int b = c[k] >> BSH;
            int pos = atomicAdd(&lcur[b], 1);
            lstage[pos] = (r[k] << BSH) | (c[k] & (BPB - 1));
            lbuck[pos] = (unsigned short)b;
        }
    }
    __syncthreads();   // lcur dead after placement; reuse for bstarts scan
    // in-block scan of gbcnt -> bstarts (replaces bscan_k dispatch)
    int gv = (t < nb) ? gbcnt[t] : 0;
    lcur[t] = gv;
    __syncthreads();
    for (int off = 1; off < 1024; off <<= 1) {
        int u = (t >= off) ? lcur[t - off] : 0;
        __syncthreads();
        lcur[t] += u;
        __syncthreads();
    }
    // global destination bases: bstarts_excl + this block's per-bucket offset
    const int* rowoff = cntmat + (size_t)blockIdx.x * nb;
    if (t < nb) lh[t] = (lcur[t] - gv) + rowoff[t];
    __syncthreads();
    // copy-out: consecutive threads -> consecutive addresses within runs
    int tot = stot;
    for (int j = t; j < tot; j += 1024) {
        int b = lbuck[j];
        staging[lh[b] + (j - lstart[b])] = lstage[j];
    }
}

// ---- pass D: per bucket: [s,e) from block-reduce of gbcnt; per-node lo/hi
//      counts + LDS scan -> starts, mids, dinv, row-partitioned placement ----
__global__ __launch_bounds__(1024) void node_k(const int* __restrict__ staging,
                                               const int* __restrict__ gbcnt,
                                               int* __restrict__ starts,
                                               int* __restrict__ mids,
                                               float* __restrict__ dinv,
                                               int* __restrict__ sorted,
                                               int N, int nb, int half) {
    __shared__ int lcA[BPB], lcB[BPB], lscan[BPB], curA[BPB], curB[BPB];
    __shared__ int red[1024];
    int t = threadIdx.x, bk = blockIdx.x;
    // s = sum(gbcnt[0..bk)), e = s + gbcnt[bk]  (replaces bstarts loads)
    red[t] = (t < bk) ? gbcnt[t] : 0;
    __syncthreads();
    for (int off = 512; off > 0; off >>= 1) {
        if (t < off) red[t] += red[t + off];
        __syncthreads();
    }
    int s = red[0];
    int e = s + gbcnt[bk];
    if (t < BPB) { lcA[t] = 0; lcB[t] = 0; }
    __syncthreads();
    int hcut = half << BSH;   // pk < hcut  <=>  r < half
    for (int i = s + t; i < e; i += 1024) {
        int pk = staging[i];
        if (pk < hcut) atomicAdd(&lcA[pk & (BPB - 1)], 1);
        else           atomicAdd(&lcB[pk & (BPB - 1)], 1);
    }
    __syncthreads();
    int dA = 0, dB = 0, d = 0;
    if (t < BPB) {
        dA = lcA[t]; dB = lcB[t]; d = dA + dB;
        lscan[t] = d;
    }
    __syncthreads();
    for (int off = 1; off < BPB; off <<= 1) {
        int u = 0;
        if (t < BPB && t >= off) u = lscan[t - off];
        __syncthreads();
        if (t < BPB && t >= off) lscan[t] += u;
        __syncthreads();
    }
    if (t < BPB) {
        int excl = s + lscan[t] - d;
        curA[t] = excl;
        curB[t] = excl + dA;
        int node = bk * BPB + t;
        if (node < N) {
            starts[node] = excl;
            mids[node]   = excl + dA;
            dinv[node]   = rsqrtf((float)d + 1.0f);
        }
    }
    if (bk == nb - 1 && t == 0) starts[N] = e;
    __syncthreads();
    for (int i = s + t; i < e; i += 1024) {
        int pk = staging[i];
        int slot = (pk < hcut) ? atomicAdd(&curA[pk & (BPB - 1)], 1)
                               : atomicAdd(&curB[pk & (BPB - 1)], 1);
        sorted[slot] = pk >> BSH;
    }
}

// ---- h1' = (x @ W1) * dinv; transposed W + padded LDS, b128 reads ----
__global__ __launch_bounds__(256) void xw1_k(const float* __restrict__ x,
                                             const float* __restrict__ W1,
                                             const float* __restrict__ dinv,
                                             float* __restrict__ h1p, int N) {
    __shared__ float wT[HID1 * XSP];   // wT[j*XSP+k] = W1[k*16+j]
    __shared__ float xs[16 * XSP];
    int t = threadIdx.x;
    for (int i = t; i < NF_IN * HID1; i += 256) {
        int k = i >> 4, j = i & 15;
        wT[j * XSP + k] = W1[i];
    }
    int base = blockIdx.x * 16;
    int navail = min(16, N - base);
    const float4* xp4 = (const float4*)(x + (size_t)base * NF_IN);
    for (int i = t; i < navail * 32; i += 256) {
        int nl = i >> 5, q = i & 31;
        *((float4*)&xs[nl * XSP + q * 4]) = xp4[(size_t)nl * 32 + q];
    }
    __syncthreads();
    int nl = t >> 4, j = t & 15;
    int n = base + nl;
    if (n < N) {
        float acc = 0.0f;
        const float4* xr = (const float4*)&xs[nl * XSP];
        const float4* wr = (const float4*)&wT[j * XSP];
        #pragma unroll
        for (int q = 0; q < 32; ++q) {
            float4 a = xr[q], w = wr[q];
            acc += a.x * w.x + a.y * w.y + a.z * w.z + a.w * w.w;
        }
        h1p[(size_t)n * HID1 + j] = acc * dinv[n];
    }
}

// ---- range accumulator: 2-chunk unrolled steady state + guarded tail ----
__device__ __forceinline__ void acc_range(const int* __restrict__ sorted,
                                          const float* __restrict__ src,
                                          int part, int lo, int hi, float4& acc) {
    int i0 = lo;
    for (; i0 + 8 <= hi; i0 += 8) {
        int ra = sorted[i0 + part];
        int rb = sorted[i0 + 4 + part];
        #pragma unroll
        for (int j = 0; j < 4; ++j) {
            int rja = __shfl(ra, j, 4);
            int rjb = __shfl(rb, j, 4);
            float4 ma = ((const float4*)(src + (size_t)rja * HID1))[part];
            float4 mb = ((const float4*)(src + (size_t)rjb * HID1))[part];
            acc.x += ma.x; acc.y += ma.y; acc.z += ma.z; acc.w += ma.w;
            acc.x += mb.x; acc.y += mb.y; acc.z += mb.z; acc.w += mb.w;
        }
    }
    for (; i0 < hi; i0 += 4) {
        int mi = i0 + part;
        int rm = (mi < hi) ? sorted[mi] : -1;
        #pragma unroll
        for (int j = 0; j < 4; ++j) {
            int rj = __shfl(rm, j, 4);
            if (rj >= 0) {
                float4 m = ((const float4*)(src + (size_t)rj * HID1))[part];
                acc.x += m.x; acc.y += m.y; acc.z += m.z; acc.w += m.w;
            }
        }
    }
}

// ---- merged gather: lo phase then hi phase + self + epilogue ----
__global__ __launch_bounds__(256) void gather_k(const int* __restrict__ sorted,
                                                const int* __restrict__ starts,
                                                const int* __restrict__ mids,
                                                const float* __restrict__ dinv,
                                                const float* __restrict__ src,
                                                const float* __restrict__ bias,
                                                float* __restrict__ dst,
                                                int N, int relu_mode) {
    int t = blockIdx.x * blockDim.x + threadIdx.x;
    int n = t >> 2, part = t & 3;
    if (n >= N) return;
    int s = starts[n], m = mids[n], e = starts[n + 1];
    float4 acc = make_float4(0.f, 0.f, 0.f, 0.f);
    acc_range(sorted, src, part, s, m, acc);   // lo rows (L2-hot 3.2MB)
    acc_range(sorted, src, part, m, e, acc);   // hi rows
    float4 sf = ((const float4*)(src + (size_t)n * HID1))[part];
    acc.x += sf.x; acc.y += sf.y; acc.z += sf.z; acc.w += sf.w;
    float dn = dinv[n];
    if (relu_mode) {
        float4 b = ((const float4*)bias)[part];
        acc.x = fmaxf(acc.x * dn + b.x, 0.f) * dn;
        acc.y = fmaxf(acc.y * dn + b.y, 0.f) * dn;
        acc.z = fmaxf(acc.z * dn + b.z, 0.f) * dn;
        acc.w = fmaxf(acc.w * dn + b.w, 0.f) * dn;
    } else {
        acc.x *= dn; acc.y *= dn; acc.z *= dn; acc.w *= dn;
    }
    ((float4*)(dst + (size_t)n * HID1))[part] = acc;
}

// ---- epilogue: y = relu(v@W2+b2); p = y@fcW; reduce; atomic pool;
//      LAST block computes log_softmax inline (threadfence + counter) ----
__global__ __launch_bounds__(256) void final_k(const float* __restrict__ v2,
                                               const float* __restrict__ W2,
                                               const float* __restrict__ b2,
                                               const float* __restrict__ fcW,
                                               const float* __restrict__ fcb,
                                               float* __restrict__ pooled,
                                               int* __restrict__ done,
                                               float* __restrict__ out,
                                               int N, float Nf) {
    __shared__ float w2[HID1 * 64];
    __shared__ float fw[128];
    __shared__ float bb[64];
    int t = threadIdx.x;
    for (int i = t; i < HID1 * 64; i += 256) w2[i] = W2[i];
    if (t < 128) fw[t] = fcW[t];
    if (t < 64) bb[t] = b2[t];
    __syncthreads();
    int n = blockIdx.x * blockDim.x + t;
    float p0 = 0.0f, p1 = 0.0f;
    if (n < N) {
        float v[HID1];
        const float4* a4 = (const float4*)(v2 + (size_t)n * HID1);
        #pragma unroll
        for (int q = 0; q < 4; ++q) {
            float4 a = a4[q];
            v[q * 4 + 0] = a.x; v[q * 4 + 1] = a.y;
            v[q * 4 + 2] = a.z; v[q * 4 + 3] = a.w;
        }
        #pragma unroll 4
        for (int j = 0; j < 64; ++j) {
            float acc = bb[j];
            #pragma unroll
            for (int k = 0; k < HID1; ++k) acc += v[k] * w2[k * 64 + j];
            float y = fmaxf(acc, 0.0f);
            p0 += y * fw[j * 2 + 0];
            p1 += y * fw[j * 2 + 1];
        }
    }
    for (int off = 32; off > 0; off >>= 1) {
        p0 += __shfl_down(p0, off);
        p1 += __shfl_down(p1, off);
    }
    __shared__ float r0[4], r1[4];
    int wid = t >> 6, lane = t & 63;
    if (lane == 0) { r0[wid] = p0; r1[wid] = p1; }
    __syncthreads();
    if (t == 0) {
        atomicAdd(&pooled[0], r0[0] + r0[1] + r0[2] + r0[3]);
        atomicAdd(&pooled[1], r1[0] + r1[1] + r1[2] + r1[3]);
        __threadfence();
        int old = atomicAdd(done, 1);
        if (old == (int)gridDim.x - 1) {
            float q0 = __hip_atomic_load(&pooled[0], __ATOMIC_RELAXED,
                                         __HIP_MEMORY_SCOPE_AGENT) + Nf * fcb[0];
            float q1 = __hip_atomic_load(&pooled[1], __ATOMIC_RELAXED,
                                         __HIP_MEMORY_SCOPE_AGENT) + Nf * fcb[1];
            float mm = fmaxf(q0, q1);
            float lse = mm + logf(expf(q0 - mm) + expf(q1 - mm));
            out[0] = q0 - lse;
            out[1] = q1 - lse;
        }
    }
}

extern "C" void kernel_launch(void* const* d_in, const int* in_sizes, int n_in,
                              void* d_out, int out_size, void* d_ws, size_t ws_size,
                              hipStream_t stream) {
    const float* x   = (const float*)d_in[0];
    const int*   ei  = (const int*)d_in[1];
    const float* W1  = (const float*)d_in[2];
    const float* b1  = (const float*)d_in[3];
    const float* W2  = (const float*)d_in[4];
    const float* b2  = (const float*)d_in[5];
    const float* fcW = (const float*)d_in[6];
    const float* fcb = (const float*)d_in[7];
    float* out = (float*)d_out;

    int N = in_sizes[0] / NF_IN;
    int E = in_sizes[1] / 2;
    const int* row = ei;
    const int* col = ei + E;

    int nb   = (N + BPB - 1) / BPB;     // coarse buckets (391)
    int nblk = (E + EPB - 1) / EPB;     // partition blocks (391)
    int half = (N + 1) / 2;

    // ws layout (4B units):
    // [starts N+1 | mids N | gbcnt nb | dinv N | h1p 16N | z1p 16N |
    //  pooled 2 | done 1 | pad | sorted E | staging E | cntmat nblk*nb]
    int*   ws_i    = (int*)d_ws;
    int*   starts  = ws_i;
    int*   mids    = ws_i + (size_t)N + 1;
    int*   gbcnt   = mids + N;
    float* dinv    = (float*)(gbcnt + nb);
    float* h1p     = dinv + N;
    float* z1p     = h1p + (size_t)16 * N;
    float* pooled  = z1p + (size_t)16 * N;
    int*   done    = (int*)(pooled + 2);
    int*   sorted  = done + 2;
    int*   staging = sorted + (size_t)E;
    int*   cntmat  = staging + (size_t)E;

    int b = 256;
    cnt1_k<<<nblk, 1024, 0, stream>>>(col, cntmat, pooled, done, E, N, nb);
    pscan2_k<<<(nb + 3) / 4, 256, 0, stream>>>(cntmat, gbcnt, nblk, nb);
    place_k<<<nblk, 1024, 0, stream>>>(row, col, gbcnt, cntmat, staging, E, N, nb);
    node_k<<<nb, 1024, 0, stream>>>(staging, gbcnt, starts, mids, dinv, sorted,
                                    N, nb, half);
    xw1_k<<<(N + 15) / 16, b, 0, stream>>>(x, W1, dinv, h1p, N);
    long long t4 = (long long)N * 4;
    int gg = (int)((t4 + b - 1) / b);
    // layer 1: h1p -> z1p (bias+relu+dinv fused)
    gather_k<<<gg, b, 0, stream>>>(sorted, starts, mids, dinv, h1p, b1, z1p, N, 1);
    // layer 2: z1p -> h1p (v2 for final_k)
    gather_k<<<gg, b, 0, stream>>>(sorted, starts, mids, dinv, z1p, b1, h1p, N, 0);
    // FC + pool + (last block) log_softmax
    final_k<<<(N + b - 1) / b, b, 0, stream>>>(h1p, W2, b2, fcW, fcb, pooled,
                                               done, out, N, (float)N);
}

// Round 15
// 235.572 us; speedup vs baseline: 1.1443x; 1.1443x over previous
//
#include <hip/hip_runtime.h>
#include <math.h>

// GCN 2-layer + FC + global_add_pool + log_softmax.
// Round 15 = R12 structure (R14's dispatch-fusion REVERTED: replacing ~5us
// launch gaps with >5us of per-block barrier work regressed) + bf16 feature
// storage: h1p/z1p rows are 16 x bf16 = 32B (was 64B fp32). All accumulation
// stays fp32; only stored features are rounded (RNE). Halves per-edge line
// traffic AND makes the full 3.2MB feature matrix per-XCD-L2 resident
// (R14 measured gather FETCH 83.5MB vs ~65MB 8-XCD fp32 floor; bf16 floor
// ~38MB).

#define NF_IN 128
#define HID1 16
#define BSH 8                 // 256 nodes per coarse bucket
#define BPB 256
#define EPB 8192              // edges per partition block
#define MAXNB 1024
#define XSP 132               // padded LDS stride for xw1

// ---- bf16 helpers (RNE pack, cheap unpack) ----
__device__ __forceinline__ unsigned int f2b_rne(float f) {
    unsigned int u = __float_as_uint(f);
    u += 0x7FFFu + ((u >> 16) & 1u);
    return u >> 16;
}
__device__ __forceinline__ unsigned int pack2(float a, float b) {
    return f2b_rne(a) | (f2b_rne(b) << 16);
}

// ---- pass A: LDS hist -> cntmat row (no global atomics); zero pooled ----
__global__ __launch_bounds__(1024) void cnt1_k(const int* __restrict__ col,
                                               int* __restrict__ cntmat,
                                               float* __restrict__ pooled,
                                               int E, int N, int nb) {
    __shared__ int lh[MAXNB];
    int t = threadIdx.x;
    if (blockIdx.x == 0 && t < 2) pooled[t] = 0.0f;
    for (int i = t; i < nb; i += 1024) lh[i] = 0;
    __syncthreads();
    int base = blockIdx.x * EPB;
    #pragma unroll
    for (int k = 0; k < EPB / 1024; ++k) {
        int e = base + k * 1024 + t;
        if (e < E) {
            int c = col[e];
            if ((unsigned)c < (unsigned)N) atomicAdd(&lh[c >> BSH], 1);
        }
    }
    __syncthreads();
    int* rowp = cntmat + (size_t)blockIdx.x * nb;
    for (int i = t; i < nb; i += 1024) rowp[i] = lh[i];
}

// ---- pass B1: wave-per-bucket column scan of cntmat (in place) ----
__global__ __launch_bounds__(256) void pscan2_k(int* __restrict__ cntmat,
                                                int* __restrict__ gbcnt,
                                                int nblk, int nb) {
    int wave = (blockIdx.x * blockDim.x + threadIdx.x) >> 6;
    int lane = threadIdx.x & 63;
    if (wave >= nb) return;
    int run = 0;
    for (int k0 = 0; k0 < nblk; k0 += 64) {
        int k = k0 + lane;
        int v = (k < nblk) ? cntmat[(size_t)k * nb + wave] : 0;
        int incl = v;
        #pragma unroll
        for (int off = 1; off < 64; off <<= 1) {
            int u = __shfl_up(incl, off, 64);
            if (lane >= off) incl += u;
        }
        int excl = incl - v + run;
        if (k < nblk) cntmat[(size_t)k * nb + wave] = excl;
        run += __shfl(incl, 63, 64);
    }
    if (lane == 0) gbcnt[wave] = run;
}

// ---- pass B2: one block scans nb (<=512) bucket totals -> bstarts ----
__global__ __launch_bounds__(512) void bscan_k(const int* __restrict__ gbcnt,
                                               int* __restrict__ bstarts, int nb) {
    __shared__ int lds[512];
    int t = threadIdx.x;
    int v = (t < nb) ? gbcnt[t] : 0;
    lds[t] = v;
    __syncthreads();
    for (int off = 1; off < 512; off <<= 1) {
        int u = (t >= off) ? lds[t - off] : 0;
        __syncthreads();
        lds[t] += u;
        __syncthreads();
    }
    if (t < nb) bstarts[t] = lds[t] - v;
    if (t == nb - 1) bstarts[nb] = lds[t];
}

// ---- pass C: block-local LDS counting sort, then line-dense copy-out ----
__global__ __launch_bounds__(1024) void place_k(const int* __restrict__ row,
                                                const int* __restrict__ col,
                                                const int* __restrict__ bstarts,
                                                const int* __restrict__ cntmat,
                                                int* __restrict__ staging,
                                                int E, int N, int nb) {
    __shared__ int lh[MAXNB];
    __shared__ int lstart[MAXNB];
    __shared__ int lcur[MAXNB];
    __shared__ int lstage[EPB];
    __shared__ unsigned short lbuck[EPB];
    __shared__ int stot;
    int t = threadIdx.x;
    for (int i = t; i < nb; i += 1024) lh[i] = 0;
    __syncthreads();
    int base = blockIdx.x * EPB;
    int r[8], c[8];
    #pragma unroll
    for (int k = 0; k < 8; ++k) {
        int e = base + k * 1024 + t;
        if (e < E) {
            r[k] = row[e];
            c[k] = col[e];
            if ((unsigned)r[k] < (unsigned)N && (unsigned)c[k] < (unsigned)N)
                atomicAdd(&lh[c[k] >> BSH], 1);
            else r[k] = -1;
        } else r[k] = -1;
    }
    __syncthreads();
    int v = (t < nb) ? lh[t] : 0;
    lstart[t] = v;
    __syncthreads();
    for (int off = 1; off < 1024; off <<= 1) {
        int u = (t >= off) ? lstart[t - off] : 0;
        __syncthreads();
        lstart[t] += u;
        __syncthreads();
    }
    int excl = lstart[t] - v;
    __syncthreads();
    lstart[t] = excl;
    lcur[t] = excl;
    if (t == nb - 1) stot = excl + v;
    __syncthreads();
    #pragma unroll
    for (int k = 0; k < 8; ++k) {
        if (r[k] >= 0) {
            int b = c[k] >> BSH;
            int pos = atomicAdd(&lcur[b], 1);
            lstage[pos] = (r[k] << BSH) | (c[k] & (BPB - 1));
            lbuck[pos] = (unsigned short)b;
        }
    }
    const int* rowoff = cntmat + (size_t)blockIdx.x * nb;
    for (int i = t; i < nb; i += 1024) lh[i] = bstarts[i] + rowoff[i];
    __syncthreads();
    int tot = stot;
    for (int j = t; j < tot; j += 1024) {
        int b = lbuck[j];
        staging[lh[b] + (j - lstart[b])] = lstage[j];
    }
}

// ---- pass D: per bucket: lo/hi counts + LDS scan -> starts, mids, dinv,
//      row-partitioned placement ----
__global__ __launch_bounds__(1024) void node_k(const int* __restrict__ staging,
                                               const int* __restrict__ bstarts,
                                               int* __restrict__ starts,
                                               int* __restrict__ mids,
                                               float* __restrict__ dinv,
                                               int* __restrict__ sorted,
                                               int N, int nb, int half) {
    __shared__ int lcA[BPB], lcB[BPB], lscan[BPB], curA[BPB], curB[BPB];
    int t = threadIdx.x, bk = blockIdx.x;
    if (t < BPB) { lcA[t] = 0; lcB[t] = 0; }
    __syncthreads();
    int s = bstarts[bk], e = bstarts[bk + 1];
    int hcut = half << BSH;
    for (int i = s + t; i < e; i += 1024) {
        int pk = staging[i];
        if (pk < hcut) atomicAdd(&lcA[pk & (BPB - 1)], 1);
        else           atomicAdd(&lcB[pk & (BPB - 1)], 1);
    }
    __syncthreads();
    int dA = 0, dB = 0, d = 0;
    if (t < BPB) {
        dA = lcA[t]; dB = lcB[t]; d = dA + dB;
        lscan[t] = d;
    }
    __syncthreads();
    for (int off = 1; off < BPB; off <<= 1) {
        int u = 0;
        if (t < BPB && t >= off) u = lscan[t - off];
        __syncthreads();
        if (t < BPB && t >= off) lscan[t] += u;
        __syncthreads();
    }
    if (t < BPB) {
        int excl = s + lscan[t] - d;
        curA[t] = excl;
        curB[t] = excl + dA;
        int node = bk * BPB + t;
        if (node < N) {
            starts[node] = excl;
            mids[node]   = excl + dA;
            dinv[node]   = rsqrtf((float)d + 1.0f);
        }
    }
    if (bk == nb - 1 && t == 0) starts[N] = e;
    __syncthreads();
    for (int i = s + t; i < e; i += 1024) {
        int pk = staging[i];
        int slot = (pk < hcut) ? atomicAdd(&curA[pk & (BPB - 1)], 1)
                               : atomicAdd(&curB[pk & (BPB - 1)], 1);
        sorted[slot] = pk >> BSH;
    }
}

// ---- h1' = (x @ W1) * dinv, stored bf16 ----
__global__ __launch_bounds__(256) void xw1_k(const float* __restrict__ x,
                                             const float* __restrict__ W1,
                                             const float* __restrict__ dinv,
                                             unsigned short* __restrict__ h1b,
                                             int N) {
    __shared__ float wT[HID1 * XSP];
    __shared__ float xs[16 * XSP];
    int t = threadIdx.x;
    for (int i = t; i < NF_IN * HID1; i += 256) {
        int k = i >> 4, j = i & 15;
        wT[j * XSP + k] = W1[i];
    }
    int base = blockIdx.x * 16;
    int navail = min(16, N - base);
    const float4* xp4 = (const float4*)(x + (size_t)base * NF_IN);
    for (int i = t; i < navail * 32; i += 256) {
        int nl = i >> 5, q = i & 31;
        *((float4*)&xs[nl * XSP + q * 4]) = xp4[(size_t)nl * 32 + q];
    }
    __syncthreads();
    int nl = t >> 4, j = t & 15;
    int n = base + nl;
    if (n < N) {
        float acc = 0.0f;
        const float4* xr = (const float4*)&xs[nl * XSP];
        const float4* wr = (const float4*)&wT[j * XSP];
        #pragma unroll
        for (int q = 0; q < 32; ++q) {
            float4 a = xr[q], w = wr[q];
            acc += a.x * w.x + a.y * w.y + a.z * w.z + a.w * w.w;
        }
        h1b[(size_t)n * HID1 + j] = (unsigned short)f2b_rne(acc * dinv[n]);
    }
}

// ---- bf16 range accumulator: 2-chunk unrolled + guarded tail.
//  part owns 4 bf16 (8B, uint2) of the 32B row ----
__device__ __forceinline__ void acc_range_b(const int* __restrict__ sorted,
                                            const unsigned short* __restrict__ src,
                                            int part, int lo, int hi,
                                            float4& acc) {
    int i0 = lo;
    for (; i0 + 8 <= hi; i0 += 8) {
        int ra = sorted[i0 + part];
        int rb = sorted[i0 + 4 + part];
        #pragma unroll
        for (int j = 0; j < 4; ++j) {
            int rja = __shfl(ra, j, 4);
            int rjb = __shfl(rb, j, 4);
            uint2 ma = ((const uint2*)(src + (size_t)rja * HID1))[part];
            uint2 mb = ((const uint2*)(src + (size_t)rjb * HID1))[part];
            acc.x += __uint_as_float(ma.x << 16);
            acc.y += __uint_as_float(ma.x & 0xFFFF0000u);
            acc.z += __uint_as_float(ma.y << 16);
            acc.w += __uint_as_float(ma.y & 0xFFFF0000u);
            acc.x += __uint_as_float(mb.x << 16);
            acc.y += __uint_as_float(mb.x & 0xFFFF0000u);
            acc.z += __uint_as_float(mb.y << 16);
            acc.w += __uint_as_float(mb.y & 0xFFFF0000u);
        }
    }
    for (; i0 < hi; i0 += 4) {
        int mi = i0 + part;
        int rm = (mi < hi) ? sorted[mi] : -1;
        #pragma unroll
        for (int j = 0; j < 4; ++j) {
            int rj = __shfl(rm, j, 4);
            if (rj >= 0) {
                uint2 m = ((const uint2*)(src + (size_t)rj * HID1))[part];
                acc.x += __uint_as_float(m.x << 16);
                acc.y += __uint_as_float(m.x & 0xFFFF0000u);
                acc.z += __uint_as_float(m.y << 16);
                acc.w += __uint_as_float(m.y & 0xFFFF0000u);
            }
        }
    }
}

// ---- layer-1 gather: bf16 src -> relu epilogue -> bf16 dst ----
__global__ __launch_bounds__(256) void gather1_k(
        const int* __restrict__ sorted, const int* __restrict__ starts,
        const int* __restrict__ mids, const float* __restrict__ dinv,
        const unsigned short* __restrict__ src, const float* __restrict__ bias,
        unsigned short* __restrict__ dst, int N) {
    int t = blockIdx.x * blockDim.x + threadIdx.x;
    int n = t >> 2, part = t & 3;
    if (n >= N) return;
    int s = starts[n], m = mids[n], e = starts[n + 1];
    float4 acc = make_float4(0.f, 0.f, 0.f, 0.f);
    acc_range_b(sorted, src, part, s, m, acc);
    acc_range_b(sorted, src, part, m, e, acc);
    uint2 sm = ((const uint2*)(src + (size_t)n * HID1))[part];
    acc.x += __uint_as_float(sm.x << 16);
    acc.y += __uint_as_float(sm.x & 0xFFFF0000u);
    acc.z += __uint_as_float(sm.y << 16);
    acc.w += __uint_as_float(sm.y & 0xFFFF0000u);
    float dn = dinv[n];
    float4 b = ((const float4*)bias)[part];
    acc.x = fmaxf(acc.x * dn + b.x, 0.f) * dn;
    acc.y = fmaxf(acc.y * dn + b.y, 0.f) * dn;
    acc.z = fmaxf(acc.z * dn + b.z, 0.f) * dn;
    acc.w = fmaxf(acc.w * dn + b.w, 0.f) * dn;
    uint2 o;
    o.x = pack2(acc.x, acc.y);
    o.y = pack2(acc.z, acc.w);
    ((uint2*)(dst + (size_t)n * HID1))[part] = o;
}

// ---- layer-2 gather: bf16 src -> fp32 dst (v2 for final_k) ----
__global__ __launch_bounds__(256) void gather2_k(
        const int* __restrict__ sorted, const int* __restrict__ starts,
        const int* __restrict__ mids, const float* __restrict__ dinv,
        const unsigned short* __restrict__ src, float* __restrict__ dst, int N) {
    int t = blockIdx.x * blockDim.x + threadIdx.x;
    int n = t >> 2, part = t & 3;
    if (n >= N) return;
    int s = starts[n], m = mids[n], e = starts[n + 1];
    float4 acc = make_float4(0.f, 0.f, 0.f, 0.f);
    acc_range_b(sorted, src, part, s, m, acc);
    acc_range_b(sorted, src, part, m, e, acc);
    uint2 sm = ((const uint2*)(src + (size_t)n * HID1))[part];
    acc.x += __uint_as_float(sm.x << 16);
    acc.y += __uint_as_float(sm.x & 0xFFFF0000u);
    acc.z += __uint_as_float(sm.y << 16);
    acc.w += __uint_as_float(sm.y & 0xFFFF0000u);
    float dn = dinv[n];
    acc.x *= dn; acc.y *= dn; acc.z *= dn; acc.w *= dn;
    ((float4*)(dst + (size_t)n * HID1))[part] = acc;
}

// ---- epilogue: y = relu(v@W2 + b2); p = y@fcW; reduce; atomic pool ----
__global__ __launch_bounds__(256) void final_k(const float* __restrict__ v2,
                                               const float* __restrict__ W2,
                                               const float* __restrict__ b2,
                                               const float* __restrict__ fcW,
                                               float* __restrict__ pooled, int N) {
    __shared__ float w2[HID1 * 64];
    __shared__ float fw[128];
    __shared__ float bb[64];
    int t = threadIdx.x;
    for (int i = t; i < HID1 * 64; i += 256) w2[i] = W2[i];
    if (t < 128) fw[t] = fcW[t];
    if (t < 64) bb[t] = b2[t];
    __syncthreads();
    int n = blockIdx.x * blockDim.x + t;
    float p0 = 0.0f, p1 = 0.0f;
    if (n < N) {
        float v[HID1];
        const float4* a4 = (const float4*)(v2 + (size_t)n * HID1);
        #pragma unroll
        for (int q = 0; q < 4; ++q) {
            float4 a = a4[q];
            v[q * 4 + 0] = a.x; v[q * 4 + 1] = a.y;
            v[q * 4 + 2] = a.z; v[q * 4 + 3] = a.w;
        }
        #pragma unroll 4
        for (int j = 0; j < 64; ++j) {
            float acc = bb[j];
            #pragma unroll
            for (int k = 0; k < HID1; ++k) acc += v[k] * w2[k * 64 + j];
            float y = fmaxf(acc, 0.0f);
            p0 += y * fw[j * 2 + 0];
            p1 += y * fw[j * 2 + 1];
        }
    }
    for (int off = 32; off > 0; off >>= 1) {
        p0 += __shfl_down(p0, off);
        p1 += __shfl_down(p1, off);
    }
    __shared__ float r0[4], r1[4];
    int wid = t >> 6, lane = t & 63;
    if (lane == 0) { r0[wid] = p0; r1[wid] = p1; }
    __syncthreads();
    if (t == 0) {
        atomicAdd(&pooled[0], r0[0] + r0[1] + r0[2] + r0[3]);
        atomicAdd(&pooled[1], r1[0] + r1[1] + r1[2] + r1[3]);
    }
}

// ---- log_softmax over pooled[2] + N*fcb ----
__global__ void logsm_k(const float* __restrict__ pooled,
                        const float* __restrict__ fcb,
                        float* __restrict__ out, float Nf) {
    if (threadIdx.x == 0 && blockIdx.x == 0) {
        float p0 = pooled[0] + Nf * fcb[0];
        float p1 = pooled[1] + Nf * fcb[1];
        float m = fmaxf(p0, p1);
        float lse = m + logf(expf(p0 - m) + expf(p1 - m));
        out[0] = p0 - lse;
        out[1] = p1 - lse;
    }
}

extern "C" void kernel_launch(void* const* d_in, const int* in_sizes, int n_in,
                              void* d_out, int out_size, void* d_ws, size_t ws_size,
                              hipStream_t stream) {
    const float* x   = (const float*)d_in[0];
    const int*   ei  = (const int*)d_in[1];
    const float* W1  = (const float*)d_in[2];
    const float* b1  = (const float*)d_in[3];
    const float* W2  = (const float*)d_in[4];
    const float* b2  = (const float*)d_in[5];
    const float* fcW = (const float*)d_in[6];
    const float* fcb = (const float*)d_in[7];
    float* out = (float*)d_out;

    int N = in_sizes[0] / NF_IN;
    int E = in_sizes[1] / 2;
    const int* row = ei;
    const int* col = ei + E;

    int nb   = (N + BPB - 1) / BPB;     // coarse buckets (391)
    int nblk = (E + EPB - 1) / EPB;     // partition blocks (391)
    int half = (N + 1) / 2;

    // ws layout (4B units):
    // [starts N+1 | mids N | bstarts nb+1 | gbcnt nb | dinv N |
    //  h1 region 16N (bf16 h1 in first 8N; later fp32 v2 uses all 16N) |
    //  z1 region 8N (bf16) | pooled 2 | sorted E | staging E | cntmat nblk*nb]
    int*   ws_i    = (int*)d_ws;
    int*   starts  = ws_i;
    int*   mids    = ws_i + (size_t)N + 1;
    int*   bstarts = mids + N;
    int*   gbcnt   = bstarts + nb + 1;
    float* dinv    = (float*)(gbcnt + nb);
    float* h1reg   = dinv + N;                      // 16N floats
    unsigned short* h1b = (unsigned short*)h1reg;   // bf16 view (8N floats used)
    unsigned short* z1b = (unsigned short*)(h1reg + (size_t)16 * N); // 8N floats
    float* pooled  = h1reg + (size_t)24 * N;
    int*   sorted  = (int*)(pooled + 2);
    int*   staging = sorted + (size_t)E;
    int*   cntmat  = staging + (size_t)E;

    int b = 256;
    cnt1_k<<<nblk, 1024, 0, stream>>>(col, cntmat, pooled, E, N, nb);
    pscan2_k<<<(nb + 3) / 4, 256, 0, stream>>>(cntmat, gbcnt, nblk, nb);
    bscan_k<<<1, 512, 0, stream>>>(gbcnt, bstarts, nb);
    place_k<<<nblk, 1024, 0, stream>>>(row, col, bstarts, cntmat, staging, E, N, nb);
    node_k<<<nb, 1024, 0, stream>>>(staging, bstarts, starts, mids, dinv, sorted,
                                    N, nb, half);
    xw1_k<<<(N + 15) / 16, b, 0, stream>>>(x, W1, dinv, h1b, N);
    long long t4 = (long long)N * 4;
    int gg = (int)((t4 + b - 1) / b);
    // layer 1: h1b -> z1b (bias+relu+dinv fused, bf16 out)
    gather1_k<<<gg, b, 0, stream>>>(sorted, starts, mids, dinv, h1b, b1, z1b, N);
    // layer 2: z1b -> v2 fp32 (reuses h1 region; h1 features dead)
    gather2_k<<<gg, b, 0, stream>>>(sorted, starts, mids, dinv, z1b, h1reg, N);
    final_k<<<(N + b - 1) / b, b, 0, stream>>>(h1reg, W2, b2, fcW, pooled, N);
    logsm_k<<<1, 64, 0, stream>>>(pooled, fcb, out, (float)N);
}